// Round 4
// baseline (241.159 us; speedup 1.0000x reference)
//
#include <hip/hip_runtime.h>

// Problem constants
#define NB 8
#define CH 64
#define KP 8            // K = C/8
#define HWP 4096        // H*W
#define QSPLIT 8        // q-split factor
#define QCHUNK (HWP / QSPLIT)   // 512 q per chunk
#define NHW (NB * HWP)  // 32768

typedef float f32x16 __attribute__((ext_vector_type(16)));
typedef __bf16 bf16x8 __attribute__((ext_vector_type(8)));
typedef short short8v __attribute__((ext_vector_type(8)));

// Workspace layout (float offsets)
#define WS_FB  0                        // f bf16 [NB][HWP][8], pre-scaled by log2(e)
#define WS_GB  (WS_FB + NHW * 4)        // g bf16 [NB][HWP][8]
#define WS_S   (WS_GB + NHW * 4)        // s f32  [NB][HWP]
#define WS_PL  (WS_S + NHW)             // partial l   [QSPLIT][NHW]
#define WS_PA  (WS_PL + QSPLIT * NHW)   // partial acc [QSPLIT][NHW]
// total = 2*131072 + 32768 + 2*262144 = 819,200 floats = 3.125 MiB

// ---------------------------------------------------------------------------
// Kernel 1: 1x1-conv projections. One thread per pixel. f pre-scaled by
// log2(e) so MFMA scores are direct exp2 arguments. f,g bf16 rows of 8; s f32.
// ---------------------------------------------------------------------------
__global__ __launch_bounds__(128) void proj_kernel(
    const float* __restrict__ x,
    const float* __restrict__ Wf, const float* __restrict__ bf,
    const float* __restrict__ Wg, const float* __restrict__ bg,
    const float* __restrict__ Ws, const float* __restrict__ bs,
    float* __restrict__ ws)
{
    int blk = blockIdx.x;                 // 256 blocks: 32 per batch
    int n = blk >> 5;
    int p = ((blk & 31) << 7) + threadIdx.x;
    const float* xp = x + (size_t)n * CH * HWP + p;

    float accf[KP], accg[KP], accs;
#pragma unroll
    for (int k = 0; k < KP; ++k) { accf[k] = bf[k]; accg[k] = bg[k]; }
    accs = bs[0];

#pragma unroll 16
    for (int c = 0; c < CH; ++c) {
        float xv = xp[(size_t)c * HWP];
#pragma unroll
        for (int k = 0; k < KP; ++k) {
            accf[k] = fmaf(Wf[k * CH + c], xv, accf[k]);
            accg[k] = fmaf(Wg[k * CH + c], xv, accg[k]);
        }
        accs = fmaf(Ws[c], xv, accs);
    }

    const float L2E = 1.4426950408889634f;
    bf16x8 fv, gv;
#pragma unroll
    for (int k = 0; k < KP; ++k) {
        fv[k] = (__bf16)(accf[k] * L2E);
        gv[k] = (__bf16)accg[k];
    }

    ushort* fb = (ushort*)(ws + WS_FB) + (size_t)(n * HWP + p) * 8;
    ushort* gb = (ushort*)(ws + WS_GB) + (size_t)(n * HWP + p) * 8;
    *(short8v*)fb = __builtin_bit_cast(short8v, fv);
    *(short8v*)gb = __builtin_bit_cast(short8v, gv);
    ws[WS_S + (size_t)n * HWP + p] = accs;
}

// ---------------------------------------------------------------------------
// Kernel 2: MFMA flash-attention partials (no-max, log2-domain).
// Block: batch n, 128 p-rows (4 waves x 32 p each), one 512-q chunk.
// Per 32-q tile: 1 A-frag (g rows; hi lanes = zero k-half) + 1 MFMA
// (32x32x16 -> S^T[32q][32p]), exp2 in place on C regs, 4-way split l/a
// accumulator chains, s from LDS per use (2-way broadcast, free).
// ---------------------------------------------------------------------------
__global__ __launch_bounds__(256, 8) void attn_mfma_kernel(float* __restrict__ ws)
{
    __shared__ alignas(16) ushort g_lds[(QCHUNK + 1) * 8];  // 8.2 KiB (+ zero row)
    __shared__ alignas(16) float  s_lds[QCHUNK];            // 2 KiB

    const int b     = blockIdx.x;          // 2048 = n(8) * pblk(32) * chunk(8)
    const int chunk = b & (QSPLIT - 1);
    const int pblk  = (b >> 3) & 31;
    const int n     = b >> 8;
    const int tid   = threadIdx.x;
    const int lane  = tid & 63;
    const int wv    = tid >> 6;
    const int l31   = lane & 31;
    const int hi    = lane >> 5;
    const int q0    = chunk * QCHUNK;

    // ---- stage g chunk (bf16, 8 KiB) + zero row + s chunk (2 KiB) ----
    {
        const float4* gsrc = (const float4*)(ws + WS_GB) + ((size_t)n * HWP + q0);
        float4* gdst = (float4*)g_lds;
        gdst[tid]       = gsrc[tid];
        gdst[tid + 256] = gsrc[tid + 256];
        if (tid == 0) gdst[QCHUNK] = make_float4(0.f, 0.f, 0.f, 0.f);
        if (tid < QCHUNK / 4)
            ((float4*)s_lds)[tid] =
                ((const float4*)(ws + WS_S + (size_t)n * HWP + q0))[tid];
    }

    // ---- B-fragment: f rows for this wave's 32 p (lanes 0-31 real) ----
    const int p0 = (pblk << 7) + (wv << 5);
    const ushort* fbase = (const ushort*)(ws + WS_FB) + (size_t)n * HWP * 8;
    short8v z8 = {0, 0, 0, 0, 0, 0, 0, 0};
    bf16x8 bfrag = __builtin_bit_cast(bf16x8,
        hi ? z8 : *(const short8v*)(fbase + (size_t)(p0 + l31) * 8));

    __syncthreads();

    const f32x16 czero = {0.f};
    float lac0 = 0.f, lac1 = 0.f, lac2 = 0.f, lac3 = 0.f;
    float aac0 = 0.f, aac1 = 0.f, aac2 = 0.f, aac3 = 0.f;

    for (int qt = 0; qt < QCHUNK / 32; ++qt) {     // 16 iterations
        const int qq = qt << 5;
        // A-frag: g rows (lanes 0-31), zero row for lanes 32-63 (k>=8)
        int arow = hi ? QCHUNK : (qq + l31);
        bf16x8 afrag = __builtin_bit_cast(bf16x8,
            *(const short8v*)(g_lds + (size_t)arow * 8));

        f32x16 c = __builtin_amdgcn_mfma_f32_32x32x16_bf16(afrag, bfrag, czero, 0, 0, 0);
        // c[r] = log2-score S2[q0+qq+(r&3)+8*(r>>2)+4*hi][p0+l31]
#pragma unroll
        for (int r = 0; r < 16; ++r) c[r] = __builtin_amdgcn_exp2f(c[r]);

        // s values for this lane's 16 q rows (2-way broadcast loads)
        float4 s0 = *(const float4*)(s_lds + qq +      (hi << 2));
        float4 s1 = *(const float4*)(s_lds + qq + 8  + (hi << 2));
        float4 s2 = *(const float4*)(s_lds + qq + 16 + (hi << 2));
        float4 s3 = *(const float4*)(s_lds + qq + 24 + (hi << 2));

        lac0 += c[0];  aac0 = fmaf(c[0],  s0.x, aac0);
        lac1 += c[1];  aac1 = fmaf(c[1],  s0.y, aac1);
        lac2 += c[2];  aac2 = fmaf(c[2],  s0.z, aac2);
        lac3 += c[3];  aac3 = fmaf(c[3],  s0.w, aac3);
        lac0 += c[4];  aac0 = fmaf(c[4],  s1.x, aac0);
        lac1 += c[5];  aac1 = fmaf(c[5],  s1.y, aac1);
        lac2 += c[6];  aac2 = fmaf(c[6],  s1.z, aac2);
        lac3 += c[7];  aac3 = fmaf(c[7],  s1.w, aac3);
        lac0 += c[8];  aac0 = fmaf(c[8],  s2.x, aac0);
        lac1 += c[9];  aac1 = fmaf(c[9],  s2.y, aac1);
        lac2 += c[10]; aac2 = fmaf(c[10], s2.z, aac2);
        lac3 += c[11]; aac3 = fmaf(c[11], s2.w, aac3);
        lac0 += c[12]; aac0 = fmaf(c[12], s3.x, aac0);
        lac1 += c[13]; aac1 = fmaf(c[13], s3.y, aac1);
        lac2 += c[14]; aac2 = fmaf(c[14], s3.z, aac2);
        lac3 += c[15]; aac3 = fmaf(c[15], s3.w, aac3);
    }

    float lsum = (lac0 + lac1) + (lac2 + lac3);
    float asum = (aac0 + aac1) + (aac2 + aac3);
    // merge hi/lo lane halves (same p, disjoint q rows)
    lsum += __shfl_xor(lsum, 32, 64);
    asum += __shfl_xor(asum, 32, 64);

    // lanes 0-31 write l, lanes 32-63 write a (both coalesced 128B)
    size_t base = (size_t)chunk * NHW + (size_t)n * HWP + p0;
    float* dst = ws + (hi ? WS_PA : WS_PL) + base + l31;
    *dst = hi ? asum : lsum;
}

// ---------------------------------------------------------------------------
// Kernel 3 (fused merge + epilogue): per block = (n, 128-p tile):
// reduce QSPLIT partials -> att (write att_map), then broadcast att over the
// 64 channels: out = att*gamma + x, float4.
// ---------------------------------------------------------------------------
__global__ __launch_bounds__(256) void finish_kernel(
    const float* __restrict__ x, const float* __restrict__ ws,
    const float* __restrict__ gamma, float* __restrict__ out)
{
    __shared__ float att_lds[128];
    const int blk = blockIdx.x;        // 256 = n(8) * pt(32)
    const int n   = blk >> 5;
    const int p0  = (blk & 31) << 7;
    const int tid = threadIdx.x;

    if (tid < 128) {
        size_t row = (size_t)n * HWP + p0 + tid;
        float l = 0.f, a = 0.f;
#pragma unroll
        for (int c = 0; c < QSPLIT; ++c) {
            l += ws[WS_PL + (size_t)c * NHW + row];
            a += ws[WS_PA + (size_t)c * NHW + row];
        }
        float att = a / l;
        att_lds[tid] = att;
        out[row] = att;                // att_map output
    }
    __syncthreads();

    const float gm = gamma[0];
    float* outp = out + NHW;
#pragma unroll
    for (int it = 0; it < 8; ++it) {
        int idx = it * 256 + tid;      // 0..2047 over (c, p/4)
        int c   = idx >> 5;
        int p4  = (idx & 31) << 2;
        size_t off = (size_t)n * CH * HWP + (size_t)c * HWP + p0 + p4;
        float4 xv = *(const float4*)(x + off);
        float4 av = *(const float4*)(att_lds + p4);
        float4 o;
        o.x = fmaf(av.x, gm, xv.x);
        o.y = fmaf(av.y, gm, xv.y);
        o.z = fmaf(av.z, gm, xv.z);
        o.w = fmaf(av.w, gm, xv.w);
        *(float4*)(outp + off) = o;
    }
}

extern "C" void kernel_launch(void* const* d_in, const int* in_sizes, int n_in,
                              void* d_out, int out_size, void* d_ws, size_t ws_size,
                              hipStream_t stream) {
    const float* x     = (const float*)d_in[0];
    const float* Wf    = (const float*)d_in[1];
    const float* bf    = (const float*)d_in[2];
    const float* Wg    = (const float*)d_in[3];
    const float* bg    = (const float*)d_in[4];
    const float* Ws    = (const float*)d_in[5];
    const float* bs    = (const float*)d_in[6];
    const float* gamma = (const float*)d_in[7];
    float* out = (float*)d_out;
    float* ws  = (float*)d_ws;

    // d_out layout: att_map [NB*HWP] then output [NB*CH*HWP]
    proj_kernel<<<NB * (HWP / 128), 128, 0, stream>>>(x, Wf, bf, Wg, bg, Ws, bs, ws);
    attn_mfma_kernel<<<NB * 32 * QSPLIT, 256, 0, stream>>>(ws);
    finish_kernel<<<NB * 32, 256, 0, stream>>>(x, ws, gamma, out);
}

// Round 5
// 38.561 us; speedup vs baseline: 6.2540x; 6.2540x over previous
//
#include <hip/hip_runtime.h>

// Problem constants
#define NB 8
#define CH 64
#define KP 8            // K = C/8
#define HWP 4096        // H*W
#define QSPLIT 8        // q-split factor
#define QCHUNK (HWP / QSPLIT)   // 512 q per chunk
#define NHW (NB * HWP)  // 32768

typedef float f32x16 __attribute__((ext_vector_type(16)));
typedef __bf16 bf16x8 __attribute__((ext_vector_type(8)));
typedef short short8v __attribute__((ext_vector_type(8)));

// Workspace layout (float offsets)
#define WS_FB  0                        // f bf16 [NB][HWP][8], pre-scaled by log2(e)
#define WS_GB  (WS_FB + NHW * 4)        // g bf16 [NB][HWP][8]
#define WS_S   (WS_GB + NHW * 4)        // s f32  [NB][HWP]
#define WS_PL  (WS_S + NHW)             // partial l   [QSPLIT][NHW]
#define WS_PA  (WS_PL + QSPLIT * NHW)   // partial acc [QSPLIT][NHW]
// total = 2*131072 + 32768 + 2*262144 = 819,200 floats = 3.125 MiB

// ---------------------------------------------------------------------------
// Kernel 1: 1x1-conv projections. One thread per pixel. f pre-scaled by
// log2(e) so MFMA scores are direct exp2 arguments. f,g bf16 rows of 8; s f32.
// ---------------------------------------------------------------------------
__global__ __launch_bounds__(128) void proj_kernel(
    const float* __restrict__ x,
    const float* __restrict__ Wf, const float* __restrict__ bf,
    const float* __restrict__ Wg, const float* __restrict__ bg,
    const float* __restrict__ Ws, const float* __restrict__ bs,
    float* __restrict__ ws)
{
    int blk = blockIdx.x;                 // 256 blocks: 32 per batch
    int n = blk >> 5;
    int p = ((blk & 31) << 7) + threadIdx.x;
    const float* xp = x + (size_t)n * CH * HWP + p;

    float accf[KP], accg[KP], accs;
#pragma unroll
    for (int k = 0; k < KP; ++k) { accf[k] = bf[k]; accg[k] = bg[k]; }
    accs = bs[0];

#pragma unroll 16
    for (int c = 0; c < CH; ++c) {
        float xv = xp[(size_t)c * HWP];
#pragma unroll
        for (int k = 0; k < KP; ++k) {
            accf[k] = fmaf(Wf[k * CH + c], xv, accf[k]);
            accg[k] = fmaf(Wg[k * CH + c], xv, accg[k]);
        }
        accs = fmaf(Ws[c], xv, accs);
    }

    const float L2E = 1.4426950408889634f;
    bf16x8 fv, gv;
#pragma unroll
    for (int k = 0; k < KP; ++k) {
        fv[k] = (__bf16)(accf[k] * L2E);
        gv[k] = (__bf16)accg[k];
    }

    ushort* fb = (ushort*)(ws + WS_FB) + (size_t)(n * HWP + p) * 8;
    ushort* gb = (ushort*)(ws + WS_GB) + (size_t)(n * HWP + p) * 8;
    *(short8v*)fb = __builtin_bit_cast(short8v, fv);
    *(short8v*)gb = __builtin_bit_cast(short8v, gv);
    ws[WS_S + (size_t)n * HWP + p] = accs;
}

// ---------------------------------------------------------------------------
// Kernel 2: MFMA flash-attention partials (no-max, log2-domain).
// Block: batch n, 128 p-rows (4 waves x 32 p each), one 512-q chunk.
// Per 32-q tile: 1 A-frag (g rows; hi lanes = zero k-half) + 1 MFMA
// (32x32x16 -> S^T[32q][32p]), exp2 in place on C regs, 4-way split l/a
// accumulator chains, s from LDS per use (2-way broadcast, free).
// __launch_bounds__(256, 4): 128-VGPR budget — (256,8) forced VGPR=32 and
// ~1 GB of scratch spill traffic (R4 post-mortem). Kernel wants ~60 VGPRs.
// ---------------------------------------------------------------------------
__global__ __launch_bounds__(256, 4) void attn_mfma_kernel(float* __restrict__ ws)
{
    __shared__ alignas(16) ushort g_lds[(QCHUNK + 1) * 8];  // 8.2 KiB (+ zero row)
    __shared__ alignas(16) float  s_lds[QCHUNK];            // 2 KiB

    const int b     = blockIdx.x;          // 2048 = n(8) * pblk(32) * chunk(8)
    const int chunk = b & (QSPLIT - 1);
    const int pblk  = (b >> 3) & 31;
    const int n     = b >> 8;
    const int tid   = threadIdx.x;
    const int lane  = tid & 63;
    const int wv    = tid >> 6;
    const int l31   = lane & 31;
    const int hi    = lane >> 5;
    const int q0    = chunk * QCHUNK;

    // ---- stage g chunk (bf16, 8 KiB) + zero row + s chunk (2 KiB) ----
    {
        const float4* gsrc = (const float4*)(ws + WS_GB) + ((size_t)n * HWP + q0);
        float4* gdst = (float4*)g_lds;
        gdst[tid]       = gsrc[tid];
        gdst[tid + 256] = gsrc[tid + 256];
        if (tid == 0) gdst[QCHUNK] = make_float4(0.f, 0.f, 0.f, 0.f);
        if (tid < QCHUNK / 4)
            ((float4*)s_lds)[tid] =
                ((const float4*)(ws + WS_S + (size_t)n * HWP + q0))[tid];
    }

    // ---- B-fragment: f rows for this wave's 32 p (lanes 0-31 real) ----
    const int p0 = (pblk << 7) + (wv << 5);
    const ushort* fbase = (const ushort*)(ws + WS_FB) + (size_t)n * HWP * 8;
    short8v z8 = {0, 0, 0, 0, 0, 0, 0, 0};
    bf16x8 bfrag = __builtin_bit_cast(bf16x8,
        hi ? z8 : *(const short8v*)(fbase + (size_t)(p0 + l31) * 8));

    __syncthreads();

    const f32x16 czero = {0.f};
    float lac0 = 0.f, lac1 = 0.f, lac2 = 0.f, lac3 = 0.f;
    float aac0 = 0.f, aac1 = 0.f, aac2 = 0.f, aac3 = 0.f;

    for (int qt = 0; qt < QCHUNK / 32; ++qt) {     // 16 iterations
        const int qq = qt << 5;
        // A-frag: g rows (lanes 0-31), zero row for lanes 32-63 (k>=8)
        int arow = hi ? QCHUNK : (qq + l31);
        bf16x8 afrag = __builtin_bit_cast(bf16x8,
            *(const short8v*)(g_lds + (size_t)arow * 8));

        f32x16 c = __builtin_amdgcn_mfma_f32_32x32x16_bf16(afrag, bfrag, czero, 0, 0, 0);
        // c[r] = log2-score S2[q0+qq+(r&3)+8*(r>>2)+4*hi][p0+l31]
#pragma unroll
        for (int r = 0; r < 16; ++r) c[r] = __builtin_amdgcn_exp2f(c[r]);

        // s values for this lane's 16 q rows (2-way broadcast loads)
        float4 s0 = *(const float4*)(s_lds + qq +      (hi << 2));
        float4 s1 = *(const float4*)(s_lds + qq + 8  + (hi << 2));
        float4 s2 = *(const float4*)(s_lds + qq + 16 + (hi << 2));
        float4 s3 = *(const float4*)(s_lds + qq + 24 + (hi << 2));

        lac0 += c[0];  aac0 = fmaf(c[0],  s0.x, aac0);
        lac1 += c[1];  aac1 = fmaf(c[1],  s0.y, aac1);
        lac2 += c[2];  aac2 = fmaf(c[2],  s0.z, aac2);
        lac3 += c[3];  aac3 = fmaf(c[3],  s0.w, aac3);
        lac0 += c[4];  aac0 = fmaf(c[4],  s1.x, aac0);
        lac1 += c[5];  aac1 = fmaf(c[5],  s1.y, aac1);
        lac2 += c[6];  aac2 = fmaf(c[6],  s1.z, aac2);
        lac3 += c[7];  aac3 = fmaf(c[7],  s1.w, aac3);
        lac0 += c[8];  aac0 = fmaf(c[8],  s2.x, aac0);
        lac1 += c[9];  aac1 = fmaf(c[9],  s2.y, aac1);
        lac2 += c[10]; aac2 = fmaf(c[10], s2.z, aac2);
        lac3 += c[11]; aac3 = fmaf(c[11], s2.w, aac3);
        lac0 += c[12]; aac0 = fmaf(c[12], s3.x, aac0);
        lac1 += c[13]; aac1 = fmaf(c[13], s3.y, aac1);
        lac2 += c[14]; aac2 = fmaf(c[14], s3.z, aac2);
        lac3 += c[15]; aac3 = fmaf(c[15], s3.w, aac3);
    }

    float lsum = (lac0 + lac1) + (lac2 + lac3);
    float asum = (aac0 + aac1) + (aac2 + aac3);
    // merge hi/lo lane halves (same p, disjoint q rows)
    lsum += __shfl_xor(lsum, 32, 64);
    asum += __shfl_xor(asum, 32, 64);

    // lanes 0-31 write l, lanes 32-63 write a (both coalesced 128B)
    size_t base = (size_t)chunk * NHW + (size_t)n * HWP + p0;
    float* dst = ws + (hi ? WS_PA : WS_PL) + base + l31;
    *dst = hi ? asum : lsum;
}

// ---------------------------------------------------------------------------
// Kernel 3 (fused merge + epilogue): per block = (n, 128-p tile):
// reduce QSPLIT partials -> att (write att_map), then broadcast att over the
// 64 channels: out = att*gamma + x, float4.
// ---------------------------------------------------------------------------
__global__ __launch_bounds__(256) void finish_kernel(
    const float* __restrict__ x, const float* __restrict__ ws,
    const float* __restrict__ gamma, float* __restrict__ out)
{
    __shared__ float att_lds[128];
    const int blk = blockIdx.x;        // 256 = n(8) * pt(32)
    const int n   = blk >> 5;
    const int p0  = (blk & 31) << 7;
    const int tid = threadIdx.x;

    if (tid < 128) {
        size_t row = (size_t)n * HWP + p0 + tid;
        float l = 0.f, a = 0.f;
#pragma unroll
        for (int c = 0; c < QSPLIT; ++c) {
            l += ws[WS_PL + (size_t)c * NHW + row];
            a += ws[WS_PA + (size_t)c * NHW + row];
        }
        float att = a / l;
        att_lds[tid] = att;
        out[row] = att;                // att_map output
    }
    __syncthreads();

    const float gm = gamma[0];
    float* outp = out + NHW;
#pragma unroll
    for (int it = 0; it < 8; ++it) {
        int idx = it * 256 + tid;      // 0..2047 over (c, p/4)
        int c   = idx >> 5;
        int p4  = (idx & 31) << 2;
        size_t off = (size_t)n * CH * HWP + (size_t)c * HWP + p0 + p4;
        float4 xv = *(const float4*)(x + off);
        float4 av = *(const float4*)(att_lds + p4);
        float4 o;
        o.x = fmaf(av.x, gm, xv.x);
        o.y = fmaf(av.y, gm, xv.y);
        o.z = fmaf(av.z, gm, xv.z);
        o.w = fmaf(av.w, gm, xv.w);
        *(float4*)(outp + off) = o;
    }
}

extern "C" void kernel_launch(void* const* d_in, const int* in_sizes, int n_in,
                              void* d_out, int out_size, void* d_ws, size_t ws_size,
                              hipStream_t stream) {
    const float* x     = (const float*)d_in[0];
    const float* Wf    = (const float*)d_in[1];
    const float* bf    = (const float*)d_in[2];
    const float* Wg    = (const float*)d_in[3];
    const float* bg    = (const float*)d_in[4];
    const float* Ws    = (const float*)d_in[5];
    const float* bs    = (const float*)d_in[6];
    const float* gamma = (const float*)d_in[7];
    float* out = (float*)d_out;
    float* ws  = (float*)d_ws;

    // d_out layout: att_map [NB*HWP] then output [NB*CH*HWP]
    proj_kernel<<<NB * (HWP / 128), 128, 0, stream>>>(x, Wf, bf, Wg, bg, Ws, bs, ws);
    attn_mfma_kernel<<<NB * 32 * QSPLIT, 256, 0, stream>>>(ws);
    finish_kernel<<<NB * 32, 256, 0, stream>>>(x, ws, gamma, out);
}

// Round 6
// 36.858 us; speedup vs baseline: 6.5430x; 1.0462x over previous
//
#include <hip/hip_runtime.h>

// Problem constants
#define NB 8
#define CH 64
#define KP 8            // K = C/8
#define HWP 4096        // H*W
#define QSPLIT 8        // q-split factor
#define QCHUNK (HWP / QSPLIT)   // 512 q per chunk
#define NHW (NB * HWP)  // 32768

typedef float f32x16 __attribute__((ext_vector_type(16)));
typedef __bf16 bf16x8 __attribute__((ext_vector_type(8)));
typedef short short8v __attribute__((ext_vector_type(8)));

// Workspace layout (float offsets)
#define WS_FB  0                        // f bf16 [NB][HWP][8], pre-scaled by log2(e)
#define WS_GB  (WS_FB + NHW * 4)        // g bf16 [NB][HWP][8]
#define WS_SB  (WS_GB + NHW * 4)        // s bf16 [NB][HWP], PRE-SHUFFLED per 16 (see below)
#define WS_PL  (WS_SB + NHW / 2)        // partial l   [QSPLIT][NHW]
#define WS_PA  (WS_PL + QSPLIT * NHW)   // partial acc [QSPLIT][NHW]
// total = 2*131072 + 16384 + 2*262144 = 802,816 floats ~= 3.06 MiB

// s shuffle: within each 16-block, position j holds s[porder[j]],
// porder = {0,1,2,3, 8,9,10,11, 4,5,6,7, 12,13,14,15} (an involution).
// This makes the PV MFMA's A-fragment k-order match the e-tile's C-reg
// q-order with zero cross-lane data movement.
__device__ __forceinline__ int s_shuf_idx(int i) {
    return i ^ (((((i >> 2) ^ (i >> 3)) & 1) != 0) ? 12 : 0);
}

// ---------------------------------------------------------------------------
// Kernel 1: 1x1-conv projections. One thread per pixel. f pre-scaled by
// log2(e) so MFMA scores are direct exp2 arguments. f,g bf16 rows of 8;
// s bf16 pre-shuffled.
// ---------------------------------------------------------------------------
__global__ __launch_bounds__(128) void proj_kernel(
    const float* __restrict__ x,
    const float* __restrict__ Wf, const float* __restrict__ bf,
    const float* __restrict__ Wg, const float* __restrict__ bg,
    const float* __restrict__ Ws, const float* __restrict__ bs,
    float* __restrict__ ws)
{
    int blk = blockIdx.x;                 // 256 blocks: 32 per batch
    int n = blk >> 5;
    int p = ((blk & 31) << 7) + threadIdx.x;
    const float* xp = x + (size_t)n * CH * HWP + p;

    float accf[KP], accg[KP], accs;
#pragma unroll
    for (int k = 0; k < KP; ++k) { accf[k] = bf[k]; accg[k] = bg[k]; }
    accs = bs[0];

#pragma unroll 16
    for (int c = 0; c < CH; ++c) {
        float xv = xp[(size_t)c * HWP];
#pragma unroll
        for (int k = 0; k < KP; ++k) {
            accf[k] = fmaf(Wf[k * CH + c], xv, accf[k]);
            accg[k] = fmaf(Wg[k * CH + c], xv, accg[k]);
        }
        accs = fmaf(Ws[c], xv, accs);
    }

    const float L2E = 1.4426950408889634f;
    bf16x8 fv, gv;
#pragma unroll
    for (int k = 0; k < KP; ++k) {
        fv[k] = (__bf16)(accf[k] * L2E);
        gv[k] = (__bf16)accg[k];
    }

    ushort* fb = (ushort*)(ws + WS_FB) + (size_t)(n * HWP + p) * 8;
    ushort* gb = (ushort*)(ws + WS_GB) + (size_t)(n * HWP + p) * 8;
    *(short8v*)fb = __builtin_bit_cast(short8v, fv);
    *(short8v*)gb = __builtin_bit_cast(short8v, gv);

    __bf16 sb16 = (__bf16)accs;
    ushort* sb = (ushort*)(ws + WS_SB);
    sb[(size_t)n * HWP + (p & ~15) + s_shuf_idx(p & 15)] =
        __builtin_bit_cast(ushort, sb16);
}

// ---------------------------------------------------------------------------
// Kernel 2: MFMA flash-attention partials (no-max, log2-domain, PV on MFMA).
// Block: batch n, 128 p-rows (4 waves x 32 p each), one 512-q chunk.
// Per 32-q tile:
//   1 MFMA(score): S2^T[32q][32p] = g . f^T   (K=8 real of 16; hi lanes zero)
//   16 exp2 in place on C regs
//   cast to bf16 -> B-fragments of the PV MFMA (C-layout q-order == B-frag
//   k-order under the s pre-shuffle; no cross-lane moves)
//   2 MFMA(PV): c_pv += A_s . E, A_s rows = {s, ones, s, s, ...}
// End: lane p (hi=0) holds c_pv[0] = sum e*s, c_pv[1] = sum e.
// ---------------------------------------------------------------------------
__global__ __launch_bounds__(256, 4) void attn_mfma_kernel(float* __restrict__ ws)
{
    __shared__ alignas(16) ushort g_lds[(QCHUNK + 1) * 8];  // 8.2 KiB (+ zero row)
    __shared__ alignas(16) ushort s_lds[QCHUNK];            // 1 KiB (shuffled bf16)

    const int b     = blockIdx.x;          // 2048 = n(8) * pblk(32) * chunk(8)
    const int chunk = b & (QSPLIT - 1);
    const int pblk  = (b >> 3) & 31;
    const int n     = b >> 8;
    const int tid   = threadIdx.x;
    const int lane  = tid & 63;
    const int wv    = tid >> 6;
    const int l31   = lane & 31;
    const int hi    = lane >> 5;
    const int q0    = chunk * QCHUNK;

    // ---- stage g chunk (bf16, 8 KiB) + zero row + shuffled-s chunk (1 KiB) ----
    {
        const float4* gsrc = (const float4*)(ws + WS_GB) + ((size_t)n * HWP + q0);
        float4* gdst = (float4*)g_lds;
        gdst[tid]       = gsrc[tid];
        gdst[tid + 256] = gsrc[tid + 256];
        if (tid == 0) gdst[QCHUNK] = make_float4(0.f, 0.f, 0.f, 0.f);
        if (tid < QCHUNK / 8)
            ((float4*)s_lds)[tid] =
                ((const float4*)((const ushort*)(ws + WS_SB) + (size_t)n * HWP + q0))[tid];
    }

    // ---- B-fragment (score): f rows for this wave's 32 p (lanes 0-31 real) ----
    const int p0 = (pblk << 7) + (wv << 5);
    const ushort* fbase = (const ushort*)(ws + WS_FB) + (size_t)n * HWP * 8;
    short8v z8 = {0, 0, 0, 0, 0, 0, 0, 0};
    bf16x8 bfrag = __builtin_bit_cast(bf16x8,
        hi ? z8 : *(const short8v*)(fbase + (size_t)(p0 + l31) * 8));

    __syncthreads();

    const f32x16 czero = {0.f};
    const uint ONESPK = 0x3F803F80u;    // two packed bf16 1.0
    const bool isOnesRow = (l31 == 1);  // A_s row 1 = ones; all others = s

    f32x16 c_pv = {0.f};

    for (int qt = 0; qt < QCHUNK / 32; ++qt) {     // 16 iterations
        const int qq = qt << 5;
        // A-frag (score): g rows (lanes 0-31), zero row for lanes 32-63 (k>=8)
        int arow = hi ? QCHUNK : (qq + l31);
        bf16x8 afrag = __builtin_bit_cast(bf16x8,
            *(const short8v*)(g_lds + (size_t)arow * 8));

        f32x16 c = __builtin_amdgcn_mfma_f32_32x32x16_bf16(afrag, bfrag, czero, 0, 0, 0);
        // c[r] = log2-score S2[q0+qq+(r&3)+8*(r>>2)+4*hi][p0+l31]
#pragma unroll
        for (int r = 0; r < 16; ++r) c[r] = __builtin_amdgcn_exp2f(c[r]);

        // e tiles as PV B-fragments (bf16). k-order per lane matches the
        // shuffled-s order by construction.
        bf16x8 elo, ehi;
#pragma unroll
        for (int r = 0; r < 8; ++r) { elo[r] = (__bf16)c[r]; ehi[r] = (__bf16)c[r + 8]; }

        // A_s fragments: lane reads 8 shuffled s (bf16) for its k-slots;
        // row 1 lanes substitute packed ones.
        uint4 sA = *(const uint4*)(s_lds + qq + (hi << 3));
        uint4 sB = *(const uint4*)(s_lds + qq + 16 + (hi << 3));
        uint4 a1u, a2u;
        a1u.x = isOnesRow ? ONESPK : sA.x;  a1u.y = isOnesRow ? ONESPK : sA.y;
        a1u.z = isOnesRow ? ONESPK : sA.z;  a1u.w = isOnesRow ? ONESPK : sA.w;
        a2u.x = isOnesRow ? ONESPK : sB.x;  a2u.y = isOnesRow ? ONESPK : sB.y;
        a2u.z = isOnesRow ? ONESPK : sB.z;  a2u.w = isOnesRow ? ONESPK : sB.w;

        c_pv = __builtin_amdgcn_mfma_f32_32x32x16_bf16(
            __builtin_bit_cast(bf16x8, a1u), elo, c_pv, 0, 0, 0);
        c_pv = __builtin_amdgcn_mfma_f32_32x32x16_bf16(
            __builtin_bit_cast(bf16x8, a2u), ehi, c_pv, 0, 0, 0);
    }

    // D rows: 0 = sum e*s, 1 = sum e; cols = p. Rows 0,1 live in regs 0,1 of
    // hi=0 lanes (row = (reg&3)+8*(reg>>2)+4*hi).
    if (!hi) {
        size_t base = (size_t)chunk * NHW + (size_t)n * HWP + p0;
        ws[WS_PA + base + l31] = c_pv[0];
        ws[WS_PL + base + l31] = c_pv[1];
    }
}

// ---------------------------------------------------------------------------
// Kernel 3 (fused merge + epilogue): per block = (n, 128-p tile):
// reduce QSPLIT partials -> att (write att_map), then broadcast att over the
// 64 channels: out = att*gamma + x, float4.
// ---------------------------------------------------------------------------
__global__ __launch_bounds__(256) void finish_kernel(
    const float* __restrict__ x, const float* __restrict__ ws,
    const float* __restrict__ gamma, float* __restrict__ out)
{
    __shared__ float att_lds[128];
    const int blk = blockIdx.x;        // 256 = n(8) * pt(32)
    const int n   = blk >> 5;
    const int p0  = (blk & 31) << 7;
    const int tid = threadIdx.x;

    if (tid < 128) {
        size_t row = (size_t)n * HWP + p0 + tid;
        float l = 0.f, a = 0.f;
#pragma unroll
        for (int c = 0; c < QSPLIT; ++c) {
            l += ws[WS_PL + (size_t)c * NHW + row];
            a += ws[WS_PA + (size_t)c * NHW + row];
        }
        float att = a / l;
        att_lds[tid] = att;
        out[row] = att;                // att_map output
    }
    __syncthreads();

    const float gm = gamma[0];
    float* outp = out + NHW;
#pragma unroll
    for (int it = 0; it < 8; ++it) {
        int idx = it * 256 + tid;      // 0..2047 over (c, p/4)
        int c   = idx >> 5;
        int p4  = (idx & 31) << 2;
        size_t off = (size_t)n * CH * HWP + (size_t)c * HWP + p0 + p4;
        float4 xv = *(const float4*)(x + off);
        float4 av = *(const float4*)(att_lds + p4);
        float4 o;
        o.x = fmaf(av.x, gm, xv.x);
        o.y = fmaf(av.y, gm, xv.y);
        o.z = fmaf(av.z, gm, xv.z);
        o.w = fmaf(av.w, gm, xv.w);
        *(float4*)(outp + off) = o;
    }
}

extern "C" void kernel_launch(void* const* d_in, const int* in_sizes, int n_in,
                              void* d_out, int out_size, void* d_ws, size_t ws_size,
                              hipStream_t stream) {
    const float* x     = (const float*)d_in[0];
    const float* Wf    = (const float*)d_in[1];
    const float* bf    = (const float*)d_in[2];
    const float* Wg    = (const float*)d_in[3];
    const float* bg    = (const float*)d_in[4];
    const float* Ws    = (const float*)d_in[5];
    const float* bs    = (const float*)d_in[6];
    const float* gamma = (const float*)d_in[7];
    float* out = (float*)d_out;
    float* ws  = (float*)d_ws;

    // d_out layout: att_map [NB*HWP] then output [NB*CH*HWP]
    proj_kernel<<<NB * (HWP / 128), 128, 0, stream>>>(x, Wf, bf, Wg, bg, Ws, bs, ws);
    attn_mfma_kernel<<<NB * 32 * QSPLIT, 256, 0, stream>>>(ws);
    finish_kernel<<<NB * 32, 256, 0, stream>>>(x, ws, gamma, out);
}

// Round 7
// 36.677 us; speedup vs baseline: 6.5753x; 1.0049x over previous
//
#include <hip/hip_runtime.h>

// Problem constants
#define NB 8
#define CH 64
#define KP 8            // K = C/8
#define HWP 4096        // H*W
#define QSPLIT 8        // q-split factor
#define QCHUNK (HWP / QSPLIT)   // 512 q per chunk
#define NHW (NB * HWP)  // 32768

typedef float f32x16 __attribute__((ext_vector_type(16)));
typedef __bf16 bf16x8 __attribute__((ext_vector_type(8)));
typedef short short8v __attribute__((ext_vector_type(8)));

// Workspace layout (float offsets)
#define WS_FB  0                        // f bf16 [NB][HWP][8], pre-scaled by log2(e)
#define WS_GB  (WS_FB + NHW * 4)        // g bf16 [NB][HWP][8]
#define WS_SB  (WS_GB + NHW * 4)        // s bf16 [NB][HWP], PRE-SHUFFLED per 16
#define WS_PL  (WS_SB + NHW / 2)        // partial l   [QSPLIT][NHW]
#define WS_PA  (WS_PL + QSPLIT * NHW)   // partial acc [QSPLIT][NHW]

// s shuffle: within each 16-block, position j holds s[porder[j]],
// porder = {0,1,2,3, 8,9,10,11, 4,5,6,7, 12,13,14,15} (an involution).
// Makes PV MFMA A-frag k-order match the e-tile C-reg q-order (verified R6).
__device__ __forceinline__ int s_shuf_idx(int i) {
    return i ^ (((((i >> 2) ^ (i >> 3)) & 1) != 0) ? 12 : 0);
}

// ---------------------------------------------------------------------------
// Kernel 1: 1x1-conv projections (unchanged from R6 — not the bottleneck).
// ---------------------------------------------------------------------------
__global__ __launch_bounds__(128) void proj_kernel(
    const float* __restrict__ x,
    const float* __restrict__ Wf, const float* __restrict__ bf,
    const float* __restrict__ Wg, const float* __restrict__ bg,
    const float* __restrict__ Ws, const float* __restrict__ bs,
    float* __restrict__ ws)
{
    int blk = blockIdx.x;                 // 256 blocks: 32 per batch
    int n = blk >> 5;
    int p = ((blk & 31) << 7) + threadIdx.x;
    const float* xp = x + (size_t)n * CH * HWP + p;

    float accf[KP], accg[KP], accs;
#pragma unroll
    for (int k = 0; k < KP; ++k) { accf[k] = bf[k]; accg[k] = bg[k]; }
    accs = bs[0];

#pragma unroll 16
    for (int c = 0; c < CH; ++c) {
        float xv = xp[(size_t)c * HWP];
#pragma unroll
        for (int k = 0; k < KP; ++k) {
            accf[k] = fmaf(Wf[k * CH + c], xv, accf[k]);
            accg[k] = fmaf(Wg[k * CH + c], xv, accg[k]);
        }
        accs = fmaf(Ws[c], xv, accs);
    }

    const float L2E = 1.4426950408889634f;
    bf16x8 fv, gv;
#pragma unroll
    for (int k = 0; k < KP; ++k) {
        fv[k] = (__bf16)(accf[k] * L2E);
        gv[k] = (__bf16)accg[k];
    }

    ushort* fb = (ushort*)(ws + WS_FB) + (size_t)(n * HWP + p) * 8;
    ushort* gb = (ushort*)(ws + WS_GB) + (size_t)(n * HWP + p) * 8;
    *(short8v*)fb = __builtin_bit_cast(short8v, fv);
    *(short8v*)gb = __builtin_bit_cast(short8v, gv);

    __bf16 sb16 = (__bf16)accs;
    ushort* sb = (ushort*)(ws + WS_SB);
    sb[(size_t)n * HWP + (p & ~15) + s_shuf_idx(p & 15)] =
        __builtin_bit_cast(ushort, sb16);
}

// ---------------------------------------------------------------------------
// Kernel 2: MFMA flash-attention partials (no-max, log2-domain, PV on MFMA).
// VGPR diet: per-lane stride pointers replace cndmask selects and staging
// regs; unroll 1 pins transients; __launch_bounds__(256,8) caps VGPR at 64
// (live set ~58) for 8 waves/SIMD.
// ---------------------------------------------------------------------------
__global__ __launch_bounds__(256, 8) void attn_mfma_kernel(float* __restrict__ ws)
{
    __shared__ alignas(16) ushort g_lds[(QCHUNK + 1) * 8];  // 8.2 KiB (+ zero row)
    __shared__ alignas(16) ushort s_lds[QCHUNK];            // 1 KiB (shuffled bf16)
    __shared__ alignas(16) ushort ones_lds[32];             // 64 B of bf16 1.0

    const int b     = blockIdx.x;          // 2048 = n(8) * pblk(32) * chunk(8)
    const int chunk = b & (QSPLIT - 1);
    const int pblk  = (b >> 3) & 31;
    const int n     = b >> 8;
    const int tid   = threadIdx.x;
    const int lane  = tid & 63;
    const int wv    = tid >> 6;
    const int l31   = lane & 31;
    const int hi    = lane >> 5;
    const int q0    = chunk * QCHUNK;

    // ---- stage g chunk + zero row + shuffled-s chunk + ones ----
    {
        const float4* gsrc = (const float4*)(ws + WS_GB) + ((size_t)n * HWP + q0);
        float4* gdst = (float4*)g_lds;
        gdst[tid]       = gsrc[tid];
        gdst[tid + 256] = gsrc[tid + 256];
        if (tid == 0) gdst[QCHUNK] = make_float4(0.f, 0.f, 0.f, 0.f);
        if (tid < QCHUNK / 8)
            ((float4*)s_lds)[tid] =
                ((const float4*)((const ushort*)(ws + WS_SB) + (size_t)n * HWP + q0))[tid];
        if (tid < 16) ((uint*)ones_lds)[tid] = 0x3F803F80u;
    }

    // ---- B-fragment (score): f rows for this wave's 32 p (lanes 0-31 real) ----
    const int p0 = (pblk << 7) + (wv << 5);
    const ushort* fbase = (const ushort*)(ws + WS_FB) + (size_t)n * HWP * 8;
    short8v z8 = {0, 0, 0, 0, 0, 0, 0, 0};
    bf16x8 bfrag = __builtin_bit_cast(bf16x8,
        hi ? z8 : *(const short8v*)(fbase + (size_t)(p0 + l31) * 8));

    // per-lane walking pointers (zero selects inside the loop):
    // g row: hi lanes pinned to the zero row (stride 0); lo lanes walk 32 rows.
    const ushort* gptr = g_lds + (size_t)(hi ? QCHUNK : l31) * 8;
    const int gstride = hi ? 0 : 32 * 8;           // ushorts per iteration
    // A_s: row-1 lanes pinned to ones (stride 0); others walk shuffled s.
    const ushort* aptr = (l31 == 1) ? ones_lds : (s_lds + (hi << 3));
    const int astride = (l31 == 1) ? 0 : 32;       // ushorts per iteration

    __syncthreads();

    const f32x16 czero = {0.f};
    f32x16 c_pv = {0.f};

#pragma unroll 1
    for (int qt = 0; qt < QCHUNK / 32; ++qt) {     // 16 iterations
        bf16x8 afrag = __builtin_bit_cast(bf16x8, *(const short8v*)gptr);
        gptr += gstride;

        f32x16 c = __builtin_amdgcn_mfma_f32_32x32x16_bf16(afrag, bfrag, czero, 0, 0, 0);
        // c[r] = log2-score S2[q0+qt*32+(r&3)+8*(r>>2)+4*hi][p0+l31]
#pragma unroll
        for (int r = 0; r < 16; ++r) c[r] = __builtin_amdgcn_exp2f(c[r]);

        // e tiles as PV B-fragments (bf16); k-order matches shuffled s.
        bf16x8 elo, ehi;
#pragma unroll
        for (int r = 0; r < 8; ++r) { elo[r] = (__bf16)c[r]; ehi[r] = (__bf16)c[r + 8]; }

        bf16x8 a1 = __builtin_bit_cast(bf16x8, *(const short8v*)aptr);
        bf16x8 a2 = __builtin_bit_cast(bf16x8, *(const short8v*)(aptr + 16));
        aptr += astride;

        c_pv = __builtin_amdgcn_mfma_f32_32x32x16_bf16(a1, elo, c_pv, 0, 0, 0);
        c_pv = __builtin_amdgcn_mfma_f32_32x32x16_bf16(a2, ehi, c_pv, 0, 0, 0);
    }

    // D rows: 0 = sum e*s, 1 = sum e; cols = p (regs 0,1 of hi=0 lanes).
    if (!hi) {
        size_t base = (size_t)chunk * NHW + (size_t)n * HWP + p0;
        ws[WS_PA + base + l31] = c_pv[0];
        ws[WS_PL + base + l31] = c_pv[1];
    }
}

// ---------------------------------------------------------------------------
// Kernel 3 (fused merge + epilogue): per block = (n, 64-p tile), 512 blocks:
// reduce QSPLIT partials -> att (write att_map), then out = att*gamma + x.
// ---------------------------------------------------------------------------
__global__ __launch_bounds__(256) void finish_kernel(
    const float* __restrict__ x, const float* __restrict__ ws,
    const float* __restrict__ gamma, float* __restrict__ out)
{
    __shared__ float att_lds[64];
    const int blk = blockIdx.x;        // 512 = n(8) * pt(64)
    const int n   = blk >> 6;
    const int p0  = (blk & 63) << 6;
    const int tid = threadIdx.x;

    if (tid < 64) {
        size_t row = (size_t)n * HWP + p0 + tid;
        float l = 0.f, a = 0.f;
#pragma unroll
        for (int c = 0; c < QSPLIT; ++c) {
            l += ws[WS_PL + (size_t)c * NHW + row];
            a += ws[WS_PA + (size_t)c * NHW + row];
        }
        float att = a / l;
        att_lds[tid] = att;
        out[row] = att;                // att_map output
    }
    __syncthreads();

    const float gm = gamma[0];
    float* outp = out + NHW;
#pragma unroll
    for (int it = 0; it < 4; ++it) {
        int idx = it * 256 + tid;      // 0..1023 over (c, p/4)
        int c   = idx >> 4;
        int p4  = (idx & 15) << 2;
        size_t off = (size_t)n * CH * HWP + (size_t)c * HWP + p0 + p4;
        float4 xv = *(const float4*)(x + off);
        float4 av = *(const float4*)(att_lds + p4);
        float4 o;
        o.x = fmaf(av.x, gm, xv.x);
        o.y = fmaf(av.y, gm, xv.y);
        o.z = fmaf(av.z, gm, xv.z);
        o.w = fmaf(av.w, gm, xv.w);
        *(float4*)(outp + off) = o;
    }
}

extern "C" void kernel_launch(void* const* d_in, const int* in_sizes, int n_in,
                              void* d_out, int out_size, void* d_ws, size_t ws_size,
                              hipStream_t stream) {
    const float* x     = (const float*)d_in[0];
    const float* Wf    = (const float*)d_in[1];
    const float* bf    = (const float*)d_in[2];
    const float* Wg    = (const float*)d_in[3];
    const float* bg    = (const float*)d_in[4];
    const float* Ws    = (const float*)d_in[5];
    const float* bs    = (const float*)d_in[6];
    const float* gamma = (const float*)d_in[7];
    float* out = (float*)d_out;
    float* ws  = (float*)d_ws;

    // d_out layout: att_map [NB*HWP] then output [NB*CH*HWP]
    proj_kernel<<<NB * (HWP / 128), 128, 0, stream>>>(x, Wf, bf, Wg, bg, Ws, bs, ws);
    attn_mfma_kernel<<<NB * 32 * QSPLIT, 256, 0, stream>>>(ws);
    finish_kernel<<<NB * 64, 256, 0, stream>>>(x, ws, gamma, out);
}